// Round 4
// baseline (288.456 us; speedup 1.0000x reference)
//
#include <hip/hip_runtime.h>
#include <stdint.h>

typedef __bf16 bf16_t;
typedef __bf16 bf16x8 __attribute__((ext_vector_type(8)));
typedef __bf16 bf16x4 __attribute__((ext_vector_type(4)));
typedef float  f32x4  __attribute__((ext_vector_type(4)));
typedef float  f32x16 __attribute__((ext_vector_type(16)));
typedef unsigned int u32;

#define L2E 1.44269504088896340736f
#define LAMBDA_INIT 0.7836057665316245f
#define ONE_MINUS_LAMBDA_INIT 0.2163942334683755f

// ---------------------------------------------------------------- helpers
__device__ __forceinline__ void gload_lds16(const void* g, void* l) {
  __builtin_amdgcn_global_load_lds(
      (const __attribute__((address_space(1))) char*)(uintptr_t)g,
      (__attribute__((address_space(3))) char*)(uintptr_t)l, 16, 0, 0);
}

__device__ __forceinline__ f32x4 mfma_bf16(bf16x8 a, bf16x8 b, f32x4 c) {
  return __builtin_amdgcn_mfma_f32_16x16x32_bf16(a, b, c, 0, 0, 0);
}
__device__ __forceinline__ f32x16 mfma32(bf16x8 a, bf16x8 b, f32x16 c) {
  return __builtin_amdgcn_mfma_f32_32x32x16_bf16(a, b, c, 0, 0, 0);
}

__device__ __forceinline__ u32 pkbf(float a, float b) {
  union { bf16_t h[2]; u32 u; } x;
  x.h[0] = (bf16_t)a; x.h[1] = (bf16_t)b;
  return x.u;
}
__device__ __forceinline__ void pl32swap(u32& a, u32& b) {
  asm volatile("v_permlane32_swap_b32 %0, %1" : "+v"(a), "+v"(b));
}

// ---------------------------------------------------------------- conversions
__global__ __launch_bounds__(256) void cvt_bf16(const float* __restrict__ in,
                                                bf16_t* __restrict__ out) {
  const size_t idx = ((size_t)blockIdx.x * 256 + threadIdx.x) * 8;
  float4 a = *(const float4*)(in + idx);
  float4 c = *(const float4*)(in + idx + 4);
  bf16x8 v;
  v[0] = (bf16_t)a.x; v[1] = (bf16_t)a.y; v[2] = (bf16_t)a.z; v[3] = (bf16_t)a.w;
  v[4] = (bf16_t)c.x; v[5] = (bf16_t)c.y; v[6] = (bf16_t)c.z; v[7] = (bf16_t)c.w;
  *(bf16x8*)(out + idx) = v;
}

// W [2048,2048] f32 -> WT [2048,2048] bf16 with WT[n][k] = W[k][n]*scale
__global__ __launch_bounds__(256) void cvt_wT(const float* __restrict__ W,
                                              bf16_t* __restrict__ WT, float scale) {
  __shared__ float t[64][65];
  const int k0 = blockIdx.x * 64, n0 = blockIdx.y * 64;
  const int r = threadIdx.x >> 2, cg = threadIdx.x & 3;
#pragma unroll
  for (int q = 0; q < 4; ++q) {
    float4 v = *(const float4*)(W + (size_t)(k0 + r) * 2048 + n0 + cg * 16 + q * 4);
    t[r][cg * 16 + q * 4 + 0] = v.x;
    t[r][cg * 16 + q * 4 + 1] = v.y;
    t[r][cg * 16 + q * 4 + 2] = v.z;
    t[r][cg * 16 + q * 4 + 3] = v.w;
  }
  __syncthreads();
  bf16x8 o0, o1;
#pragma unroll
  for (int j = 0; j < 8; ++j) o0[j] = (bf16_t)(t[cg * 16 + j][r] * scale);
#pragma unroll
  for (int j = 0; j < 8; ++j) o1[j] = (bf16_t)(t[cg * 16 + 8 + j][r] * scale);
  bf16_t* dst = WT + (size_t)(n0 + r) * 2048 + k0 + cg * 16;
  *(bf16x8*)dst = o0;
  *(bf16x8*)(dst + 8) = o1;
}

__global__ void lam_kernel(const float* lq1, const float* lk1,
                           const float* lq2, const float* lk2, float* out) {
  const int l = threadIdx.x;  // 64 threads
  float p1 = lq1[l] * lk1[l];
  float p2 = lq2[l] * lk2[l];
#pragma unroll
  for (int d = 1; d < 64; d <<= 1) {
    p1 += __shfl_xor(p1, d);
    p2 += __shfl_xor(p2, d);
  }
  if (l == 0) *out = expf(p1) - expf(p2) + LAMBDA_INIT;
}

// ---------------------------------------------------------------- GEMM
template <int OUTMODE>
__global__ __launch_bounds__(256, 2) void gemm_bt(const bf16_t* __restrict__ A,
                                                  const bf16_t* __restrict__ Bt,
                                                  void* __restrict__ Cv) {
  __shared__ __align__(16) bf16_t As[128 * 64];
  __shared__ __align__(16) bf16_t Bs[128 * 64];
  const int tid = threadIdx.x;
  const int w = tid >> 6, lane = tid & 63;
  const int wr = w >> 1, wc = w & 1;
  const int lm = lane >> 4, ln = lane & 15;
  // bijective XCD swizzle (T1): 512 blocks, 8 XCDs, 64 per XCD contiguous
  const int flat = (int)blockIdx.y * (int)gridDim.x + (int)blockIdx.x;
  const int swz = (flat & 7) * 64 + (flat >> 3);
  const int m0 = (swz & 31) * 128, n0 = (swz >> 5) * 128;

  const f32x4 vzero = {0.f, 0.f, 0.f, 0.f};
  f32x4 acc[4][4];
#pragma unroll
  for (int m = 0; m < 4; ++m)
#pragma unroll
    for (int n = 0; n < 4; ++n) acc[m][n] = vzero;

  for (int k0 = 0; k0 < 2048; k0 += 64) {
    __syncthreads();
#pragma unroll
    for (int j = 0; j < 4; ++j) {
      const int inst = w * 4 + j;
      const int row = inst * 8 + (lane >> 3);              // tile row (RS=128B)
      const int cb = ((lane & 7) * 16) ^ ((row & 7) << 4); // pre-swizzled source col
      gload_lds16(A + (size_t)(m0 + row) * 2048 + k0 + (cb >> 1),
                  (char*)As + inst * 1024);
      gload_lds16(Bt + (size_t)(n0 + row) * 2048 + k0 + (cb >> 1),
                  (char*)Bs + inst * 1024);
    }
    asm volatile("s_waitcnt vmcnt(0)" ::: "memory");
    __syncthreads();

#pragma unroll
    for (int kc = 0; kc < 2; ++kc) {
      bf16x8 af[4], bfr[4];
#pragma unroll
      for (int m = 0; m < 4; ++m) {
        const int row = wr * 64 + m * 16 + ln;
        int off = row * 128 + kc * 64 + lm * 16;
        off ^= (row & 7) << 4;
        af[m] = *(const bf16x8*)((const char*)As + off);
      }
#pragma unroll
      for (int n = 0; n < 4; ++n) {
        const int row = wc * 64 + n * 16 + ln;
        int off = row * 128 + kc * 64 + lm * 16;
        off ^= (row & 7) << 4;
        bfr[n] = *(const bf16x8*)((const char*)Bs + off);
      }
      __builtin_amdgcn_s_setprio(1);
#pragma unroll
      for (int m = 0; m < 4; ++m)
#pragma unroll
        for (int n = 0; n < 4; ++n) acc[m][n] = mfma_bf16(af[m], bfr[n], acc[m][n]);
      __builtin_amdgcn_s_setprio(0);
    }
  }

  if (OUTMODE == 0) {
    bf16_t* C = (bf16_t*)Cv;
#pragma unroll
    for (int m = 0; m < 4; ++m)
#pragma unroll
      for (int n = 0; n < 4; ++n)
#pragma unroll
        for (int r = 0; r < 4; ++r) {
          const size_t grow = m0 + wr * 64 + m * 16 + lm * 4 + r;
          const int gcol = n0 + wc * 64 + n * 16 + ln;
          C[grow * 2048 + gcol] = (bf16_t)acc[m][n][r];
        }
  } else if (OUTMODE == 1) {
    bf16_t* C = (bf16_t*)Cv;  // [2048][4096]
#pragma unroll
    for (int m = 0; m < 4; ++m)
#pragma unroll
      for (int n = 0; n < 4; ++n) {
        const size_t gcol = n0 + wc * 64 + n * 16 + ln;
        const int growb = m0 + wr * 64 + m * 16 + lm * 4;
        bf16x4 v;
#pragma unroll
        for (int r = 0; r < 4; ++r) v[r] = (bf16_t)acc[m][n][r];
        *(bf16x4*)(C + gcol * 4096 + growb) = v;
      }
  } else {
    float* C = (float*)Cv;
#pragma unroll
    for (int m = 0; m < 4; ++m)
#pragma unroll
      for (int n = 0; n < 4; ++n)
#pragma unroll
        for (int r = 0; r < 4; ++r) {
          const size_t grow = m0 + wr * 64 + m * 16 + lm * 4 + r;
          const int gcol = n0 + wc * 64 + n * 16 + ln;
          C[grow * 2048 + gcol] = acc[m][n][r];
        }
  }
}

// ---------------------------------------------------------------- flash diff-attn
// 32x32x16 MFMA, swapped operands, zero P-LDS roundtrip (T12).
// Wave w = (qh = w>>1, s = w&1): 32 q-rows (qh half), one subhead s, all 64 keys.
// QK^T: S^T[key][q] = mfma(A=K, B=Q)  -> lane holds q=lane&31 col, 32 keys in regs.
// P^T assembled in-register via cvt_pk pairs + v_permlane32_swap_b32.
// PV: O^T[d][q] = mfma(A=V^T, B=P^T), acc = 4 x f32x16 (128d x 32q per wave).
// Epilogue: s=1 wave writes O1^T/l1 to LDS; s=0 combines, RMSNorm(128), stores.
__global__ __launch_bounds__(256, 2) void flash_diff(const bf16_t* __restrict__ Q,
                                                     const bf16_t* __restrict__ K,
                                                     const bf16_t* __restrict__ Vt,
                                                     bf16_t* __restrict__ attnb,
                                                     const float* __restrict__ lamP) {
  // LDS (80KB): [0,16K) Qs; [16K,48K) K dbuf; [48K,80K) V dbuf.
  // Epilogue overlay: Obuf f32 [2][32][128] = 32KB at +16K (K region, dead then).
  __shared__ __align__(16) char smem[81920];

  const int tid = threadIdx.x;
  const int w = tid >> 6, lane = tid & 63;
  const int qh = w >> 1, s = w & 1;
  const int l31 = lane & 31, hi = lane >> 5;
  const int h = blockIdx.y, b = blockIdx.z;
  const size_t bt0 = (size_t)b * 2048;
  const float lam = *lamP;

  auto stage_kv = [&](int buf, int k0) {
#pragma unroll
    for (int j = 0; j < 4; ++j) {
      const int inst = w * 4 + j;
      {  // K tile [64][128], RS=256B
        const int row = inst * 4 + (lane >> 4);
        const int cb = ((lane & 15) * 16) ^ ((row & 7) << 4);
        gload_lds16(K + (bt0 + k0 + row) * 2048 + h * 128 + (cb >> 1),
                    smem + 16384 + buf * 16384 + inst * 1024);
      }
      {  // Vt tile [128][64], RS=128B
        const int row = inst * 8 + (lane >> 3);
        const int cb = ((lane & 7) * 16) ^ ((row & 7) << 4);
        gload_lds16(Vt + (size_t)(h * 128 + row) * 4096 + bt0 + k0 + (cb >> 1),
                    smem + 49152 + buf * 16384 + inst * 1024);
      }
    }
  };

  for (int half = 0; half < 2; ++half) {
    const int qt = half == 0 ? (int)blockIdx.x : 31 - (int)blockIdx.x;
    const int q0 = qt * 64;
    const int qloc = qh * 32 + l31;

    // stage Q tile [64][128] (RS=256B) + first K/V tile into buf0
#pragma unroll
    for (int j = 0; j < 4; ++j) {
      const int inst = w * 4 + j;
      const int row = inst * 4 + (lane >> 4);
      const int cb = ((lane & 15) * 16) ^ ((row & 7) << 4);
      gload_lds16(Q + (bt0 + q0 + row) * 2048 + h * 128 + (cb >> 1),
                  smem + inst * 1024);
    }
    stage_kv(0, 0);
    asm volatile("s_waitcnt vmcnt(0)" ::: "memory");
    __syncthreads();

    // Q B-frags: lane = col q (=l31), d-slice = s*64 + kc*16 + hi*8
    bf16x8 qf[4];
#pragma unroll
    for (int kc = 0; kc < 4; ++kc) {
      const int row = qloc;
      int off = row * 256 + s * 128 + kc * 32 + hi * 16;
      off ^= (row & 7) << 4;
      qf[kc] = *(const bf16x8*)((const char*)smem + off);
    }

    f32x16 accv[4];
#pragma unroll
    for (int m = 0; m < 4; ++m)
#pragma unroll
      for (int r = 0; r < 16; ++r) accv[m][r] = 0.f;
    float lsum = 0.f;

    int cur = 0;
    for (int kt = 0; kt <= qt; ++kt) {
      if (kt < qt) stage_kv(cur ^ 1, (kt + 1) * 64);

      const char* Ksb = (const char*)smem + 16384 + cur * 16384;
      const char* Vsb = (const char*)smem + 49152 + cur * 16384;

      // ---- QK^T swapped: S^T[key][q]
      f32x16 sa[2];
#pragma unroll
      for (int m = 0; m < 2; ++m)
#pragma unroll
        for (int r = 0; r < 16; ++r) sa[m][r] = 0.f;
      __builtin_amdgcn_s_setprio(1);
#pragma unroll
      for (int kc = 0; kc < 4; ++kc) {
#pragma unroll
        for (int mt = 0; mt < 2; ++mt) {
          const int row = mt * 32 + l31;
          int off = row * 256 + s * 128 + kc * 32 + hi * 16;
          off ^= (row & 7) << 4;
          bf16x8 kf = *(const bf16x8*)(Ksb + off);
          sa[mt] = mfma32(kf, qf[kc], sa[mt]);
        }
      }
      __builtin_amdgcn_s_setprio(0);

      if (kt == qt) {  // causal mask within diagonal tile
#pragma unroll
        for (int mt = 0; mt < 2; ++mt)
#pragma unroll
          for (int r = 0; r < 16; ++r) {
            const int key = mt * 32 + (r & 3) + 8 * (r >> 2) + 4 * hi;
            if (key > qloc) sa[mt][r] = -1e30f;
          }
      }

      // ---- exp + in-register P^T frag assembly (cvt_pk + permlane32_swap)
      bf16x8 pf[2][2];
#pragma unroll
      for (int mt = 0; mt < 2; ++mt) {
        float p[16];
#pragma unroll
        for (int r = 0; r < 16; ++r) {
          p[r] = exp2f(sa[mt][r]);
          lsum += p[r];
        }
        u32 c0 = pkbf(p[0], p[1]),   c1 = pkbf(p[2], p[3]);
        u32 c2 = pkbf(p[4], p[5]),   c3 = pkbf(p[6], p[7]);
        u32 c4 = pkbf(p[8], p[9]),   c5 = pkbf(p[10], p[11]);
        u32 c6 = pkbf(p[12], p[13]), c7 = pkbf(p[14], p[15]);
        pl32swap(c0, c2); pl32swap(c1, c3);
        pl32swap(c4, c6); pl32swap(c5, c7);
        union { u32 u[4]; bf16x8 v; } f0, f1;
        f0.u[0] = c0; f0.u[1] = c1; f0.u[2] = c2; f0.u[3] = c3;
        f1.u[0] = c4; f1.u[1] = c5; f1.u[2] = c6; f1.u[3] = c7;
        pf[mt][0] = f0.v;
        pf[mt][1] = f1.v;
      }

      // ---- PV swapped: O^T[d][q] += V^T · P^T
      __builtin_amdgcn_s_setprio(1);
#pragma unroll
      for (int mt4 = 0; mt4 < 4; ++mt4) {
        const int row = mt4 * 32 + l31;
        const int rswz = (row & 7) << 4;
#pragma unroll
        for (int st = 0; st < 4; ++st) {
          int off = row * 128 + st * 32 + hi * 16;
          off ^= rswz;
          bf16x8 vf = *(const bf16x8*)(Vsb + off);
          accv[mt4] = mfma32(vf, pf[st >> 1][st & 1], accv[mt4]);
        }
      }
      __builtin_amdgcn_s_setprio(0);

      asm volatile("s_waitcnt vmcnt(0)" ::: "memory");
      __syncthreads();
      cur ^= 1;
    }

    // ---- epilogue
    lsum += __shfl_xor(lsum, 32);
    const float rl = 1.0f / lsum;
    float* Obuf = (float*)(smem + 16384);  // [2][32][128] f32

    if (s == 1) {
#pragma unroll
      for (int mt4 = 0; mt4 < 4; ++mt4)
#pragma unroll
        for (int q2 = 0; q2 < 4; ++q2) {
          f32x4 v;
#pragma unroll
          for (int e = 0; e < 4; ++e) v[e] = accv[mt4][q2 * 4 + e] * rl;
          const int d = mt4 * 32 + q2 * 8 + hi * 4;
          *(f32x4*)(Obuf + (size_t)qloc * 128 + d) = v;
        }
    }
    __syncthreads();
    if (s == 0) {
      float o[4][16];
      float ss = 0.f;
#pragma unroll
      for (int mt4 = 0; mt4 < 4; ++mt4)
#pragma unroll
        for (int q2 = 0; q2 < 4; ++q2) {
          const int d = mt4 * 32 + q2 * 8 + hi * 4;
          f32x4 ov = *(const f32x4*)(Obuf + (size_t)qloc * 128 + d);
#pragma unroll
          for (int e = 0; e < 4; ++e) {
            const float v = accv[mt4][q2 * 4 + e] * rl - lam * ov[e];
            o[mt4][q2 * 4 + e] = v;
            ss += v * v;
          }
        }
      ss += __shfl_xor(ss, 32);
      const float sc = rsqrtf(ss * (1.0f / 128.f) + 1e-5f) * ONE_MINUS_LAMBDA_INIT;
      const size_t grow = bt0 + q0 + qloc;
#pragma unroll
      for (int mt4 = 0; mt4 < 4; ++mt4)
#pragma unroll
        for (int q2 = 0; q2 < 4; ++q2) {
          const int d = mt4 * 32 + q2 * 8 + hi * 4;
          bf16x4 v;
#pragma unroll
          for (int e = 0; e < 4; ++e) v[e] = (bf16_t)(o[mt4][q2 * 4 + e] * sc);
          *(bf16x4*)(attnb + grow * 2048 + h * 128 + d) = v;
        }
    }
    __syncthreads();  // Obuf reads done before next half re-stages K
  }
}

// ---------------------------------------------------------------- launch
extern "C" void kernel_launch(void* const* d_in, const int* in_sizes, int n_in,
                              void* d_out, int out_size, void* d_ws, size_t ws_size,
                              hipStream_t stream) {
  const float* x   = (const float*)d_in[0];
  const float* Wq  = (const float*)d_in[1];
  const float* Wk  = (const float*)d_in[2];
  const float* Wv  = (const float*)d_in[3];
  const float* Wo  = (const float*)d_in[4];
  const float* lq1 = (const float*)d_in[5];
  const float* lk1 = (const float*)d_in[6];
  const float* lq2 = (const float*)d_in[7];
  const float* lk2 = (const float*)d_in[8];

  char* ws = (char*)d_ws;
  bf16_t* xb    = (bf16_t*)(ws + 0);                 // 16 MB  [4096,2048]
  bf16_t* wqT   = (bf16_t*)(ws + 16777216);          // 8 MB
  bf16_t* wkT   = (bf16_t*)(ws + 25165824);          // 8 MB
  bf16_t* wvT   = (bf16_t*)(ws + 33554432);          // 8 MB
  bf16_t* woT   = (bf16_t*)(ws + 41943040);          // 8 MB
  bf16_t* Qb    = (bf16_t*)(ws + 50331648);          // 16 MB
  bf16_t* Kb    = (bf16_t*)(ws + 67108864);          // 16 MB
  bf16_t* Vtb   = (bf16_t*)(ws + 16777216);          // 16 MB (aliases wqT+wkT)
  bf16_t* attnb = (bf16_t*)(ws + 0);                 // 16 MB (aliases xb)
  float*  lamP  = (float*)(ws + 83886080);

  cvt_bf16<<<4096, 256, 0, stream>>>(x, xb);
  cvt_wT<<<dim3(32, 32), 256, 0, stream>>>(Wq, wqT, 0.125f * L2E);
  cvt_wT<<<dim3(32, 32), 256, 0, stream>>>(Wk, wkT, 1.0f);
  cvt_wT<<<dim3(32, 32), 256, 0, stream>>>(Wv, wvT, 1.0f);
  cvt_wT<<<dim3(32, 32), 256, 0, stream>>>(Wo, woT, 1.0f);
  lam_kernel<<<1, 64, 0, stream>>>(lq1, lk1, lq2, lk2, lamP);

  gemm_bt<0><<<dim3(32, 16), 256, 0, stream>>>(xb, wqT, (void*)Qb);
  gemm_bt<0><<<dim3(32, 16), 256, 0, stream>>>(xb, wkT, (void*)Kb);
  gemm_bt<1><<<dim3(32, 16), 256, 0, stream>>>(xb, wvT, (void*)Vtb);  // V^T out

  flash_diff<<<dim3(16, 16, 2), 256, 0, stream>>>(Qb, Kb, Vtb, attnb, lamP);

  gemm_bt<2><<<dim3(32, 16), 256, 0, stream>>>(attnb, woT, d_out);
}